// Round 5
// baseline (2626.363 us; speedup 1.0000x reference)
//
#include <hip/hip_runtime.h>

#define HF 10        // feature width
#define ST 16        // fallback-path row stride
#define BST 16       // bufC padded row stride (64 B -> 1 line per random gather)
#define SLC 256      // scatter/hist slices (WGs)
#define NBINS 2048   // src bins (512 vars/bin); also array stride for D hists
#define VPB 512      // vars per src-bin
#define TILE 12288   // scatS2 LDS tile (96 KB buf; total ~124 KB LDS)
#define NBD 1024     // dst-bin LDS array (977 used at NC=500K)
#define DSH 9        // dst shift: 512 cons per dst-bin
#define CPB 512      // cons per dst-bin (aggD block width)
#define TILED 6144   // scatD3 tile (96 KB uint4 buf; total ~112 KB LDS)

// ============================================================================
// FAST PATH v6 (request-rate aware, both scatters coalesced):
//   Model: random 64-B line requests service at ~1/cy per XCD L2
//   (16M req = 833 us floor, hit/miss-independent; verified r2-r4:
//   FETCH 952/855/813 MB all -> ~860 us). k_aggS sits AT that wall
//   structurally (one line gather per edge). Both scatter phases are now
//   LDS-tile counting sorts with per-bin coalesced run write-out:
//   S: ~6 x 8 B runs; D: ~6.3 x 16 B runs (512-con bins).
//   1) per-slice src-bin hist -> cursors              [k_hist/coltot/prefix/offs]
//   2) tile-sorted coalesced S scatter                [k_scatS2]
//   3) degrees/norm from sorted keys (streaming)      [k_cntS2]
//   4) D-phase per src-bin range from sorted buffer:
//      tile-sorted coalesced D scatter (vcx L1-hot)   [k_histD2/k_scatD3]
//   5) streaming v2c aggregation (512-con bins)       [k_aggD]
//   6) con transform                                  [k_conT]
//   7) fused c2v aggregate + @W2 + MLP + mean         [k_aggS]
// ============================================================================

// ---- per-slice histogram of idx>>shift over [s_begin, s_end) ----
__global__ __launch_bounds__(1024) void k_hist(const int* __restrict__ idx,
                                               unsigned* __restrict__ hist,
                                               long long s_begin, long long s_end,
                                               int per, int shift) {
    __shared__ unsigned l[NBINS];
    int t = threadIdx.x, sl = blockIdx.x;
    for (int b = t; b < NBINS; b += 1024) l[b] = 0u;
    __syncthreads();
    long long s0 = s_begin + (long long)sl * per;
    long long s1 = s0 + per; if (s1 > s_end) s1 = s_end;
    for (long long i = s0 + t; i < s1; i += 1024)
        atomicAdd(&l[((unsigned)idx[i]) >> shift], 1u);
    __syncthreads();
    unsigned* out = hist + (size_t)sl * NBINS;
    for (int b = t; b < NBINS; b += 1024) out[b] = l[b];
}

// ---- per-bin totals over slices (coalesced column walk) ----
__global__ void k_coltot(const unsigned* __restrict__ h, unsigned* __restrict__ colT) {
    int b = blockIdx.x * 256 + threadIdx.x;
    unsigned s = 0u;
    for (int sl = 0; sl < SLC; sl++) s += h[(size_t)sl * NBINS + b];
    colT[b] = s;
}

// ---- exclusive prefix over NBINS(2048) bin totals ----
__global__ __launch_bounds__(1024) void k_prefix(const unsigned* __restrict__ colT,
                                                 unsigned* __restrict__ start) {
    __shared__ unsigned p[1024];
    int t = threadIdx.x;
    uint2 v = *(const uint2*)(colT + 2 * t);
    unsigned own = v.x + v.y;
    p[t] = own;
    __syncthreads();
    for (int off = 1; off < 1024; off <<= 1) {
        unsigned u = (t >= off) ? p[t - off] : 0u;
        __syncthreads();
        p[t] += u;
        __syncthreads();
    }
    unsigned e = p[t] - own;
    *(uint2*)(start + 2 * t) = make_uint2(e, e + v.x);
    if (t == 1023) start[NBINS] = p[1023];
}

// ---- per-slice exclusive cursors, written in place over h ----
__global__ void k_offs(unsigned* __restrict__ h, const unsigned* __restrict__ start) {
    int b = blockIdx.x * 256 + threadIdx.x;
    unsigned cur = start[b];
    for (int sl = 0; sl < SLC; sl++) {
        unsigned* cell = h + (size_t)sl * NBINS + b;
        unsigned v = *cell;
        *cell = cur;
        cur += v;
    }
}

// ---- S scatter: LDS tile counting-sort + per-bin coalesced run write-out.
//      key=(slow9<<19)|dst19, payload A. ----
__global__ __launch_bounds__(1024) void k_scatS2(
        const int* __restrict__ src, const int* __restrict__ dst,
        const float* __restrict__ A, const unsigned* __restrict__ offs,
        uint2* __restrict__ ebufS, long long E, int per) {
    __shared__ unsigned cur[NBINS];
    __shared__ unsigned th[NBINS];
    __shared__ unsigned tf[NBINS];
    __shared__ unsigned sc[1024];
    __shared__ __align__(16) uint2 buf[TILE];
    int t = threadIdx.x, sl = blockIdx.x;
    const unsigned* o = offs + (size_t)sl * NBINS;
    for (int b = t; b < NBINS; b += 1024) cur[b] = o[b];
    long long s0 = (long long)sl * per;
    long long s1 = s0 + per; if (s1 > E) s1 = E;
    for (long long tb = s0; tb < s1; tb += TILE) {
        int n = (int)((s1 - tb < (long long)TILE) ? (s1 - tb) : (long long)TILE);
        for (int b = t; b < NBINS; b += 1024) th[b] = 0u;
        __syncthreads();
        for (int i = t; i < n; i += 1024)
            atomicAdd(&th[((unsigned)src[tb + i]) >> 9], 1u);
        __syncthreads();
        unsigned a0 = th[2 * t], a1 = th[2 * t + 1];
        unsigned own = a0 + a1;
        sc[t] = own;
        __syncthreads();
        for (int off = 1; off < 1024; off <<= 1) {
            unsigned u = (t >= off) ? sc[t - off] : 0u;
            __syncthreads();
            sc[t] += u;
            __syncthreads();
        }
        unsigned ex = sc[t] - own;
        th[2 * t] = ex;     th[2 * t + 1] = ex + a0;
        tf[2 * t] = ex;     tf[2 * t + 1] = ex + a0;
        __syncthreads();
        for (int i = t; i < n; i += 1024) {
            unsigned s = (unsigned)src[tb + i], d = (unsigned)dst[tb + i];
            float a = A[tb + i];
            unsigned p = atomicAdd(&tf[s >> 9], 1u);
            buf[p] = make_uint2(((s & 511u) << 19) | d, __float_as_uint(a));
        }
        __syncthreads();
        int w = t >> 6, ln = t & 63;
        for (int b = w; b < NBINS; b += 16) {
            unsigned lo = th[b], cnt = tf[b] - lo, gb = cur[b];
            for (unsigned j = ln; j < cnt; j += 64)
                ebufS[gb + j] = buf[lo + j];
        }
        __syncthreads();
        for (int b = t; b < NBINS; b += 1024) cur[b] += tf[b] - th[b];
        __syncthreads();
    }
}

// ---- degrees from sorted S keys -> vcx[v]=(c,x,rsqrt(max(deg,1)),0) ----
__global__ void k_cntS2(const uint2* __restrict__ ebufS, const unsigned* __restrict__ startS,
                        const float* __restrict__ var_c, const float* __restrict__ var_x,
                        float4* __restrict__ vcx, int NV) {
    __shared__ unsigned cnt[VPB];
    int t = threadIdx.x, b = blockIdx.x;
    cnt[t] = 0u; cnt[t + 256] = 0u;
    __syncthreads();
    unsigned i0 = startS[b], i1 = startS[b + 1];
    for (unsigned i = i0 + t; i < i1; i += 256)
        atomicAdd(&cnt[ebufS[i].x >> 19], 1u);
    __syncthreads();
#pragma unroll
    for (int k = 0; k < 2; k++) {
        int v = b * VPB + k * 256 + t;
        if (v < NV)
            vcx[v] = make_float4(var_c[v], var_x[v],
                                 rsqrtf(fmaxf((float)cnt[k * 256 + t], 1.0f)), 0.0f);
    }
}

// ---- D hist: dst-bin (>>DSH) histogram from the SORTED edge buffer. ----
__global__ __launch_bounds__(1024) void k_histD2(const uint2* __restrict__ ebufB,
                                                 const unsigned* __restrict__ startS,
                                                 unsigned* __restrict__ hist, int B0, int binsPer) {
    __shared__ unsigned l[NBINS];
    int t = threadIdx.x, sl = blockIdx.x;
    for (int b = t; b < NBINS; b += 1024) l[b] = 0u;
    __syncthreads();
    int b0 = B0 + sl * binsPer;
    unsigned i0 = startS[b0], i1 = startS[b0 + binsPer];
    for (unsigned i = i0 + t; i < i1; i += 1024)
        atomicAdd(&l[(ebufB[i].x & 0x7FFFFu) >> DSH], 1u);
    __syncthreads();
    unsigned* out = hist + (size_t)sl * NBINS;
    for (int b = t; b < NBINS; b += 1024) out[b] = l[b];
}

// ---- v6 D scatter: per-src-bin walk (vcx L1-hot), LDS tile counting-sort
//      by dst>>DSH, per-bin coalesced run write-out (~100-B runs). ----
__global__ __launch_bounds__(1024) void k_scatD3(
        const uint2* __restrict__ ebufB, const unsigned* __restrict__ startS,
        const unsigned* __restrict__ offs, const float4* __restrict__ vcx,
        uint4* __restrict__ ebufD, int B0, int binsPer, unsigned cap) {
    __shared__ unsigned cur[NBD];
    __shared__ unsigned th[NBD], tf[NBD];
    __shared__ unsigned sc[1024];
    __shared__ __align__(16) uint4 buf[TILED];
    int t = threadIdx.x, sl = blockIdx.x;
    const unsigned* o = offs + (size_t)sl * NBINS;
    cur[t] = o[t];                       // NBD == blockDim == 1024
    __syncthreads();
    int b0 = B0 + sl * binsPer;
    for (int bb = 0; bb < binsPer; bb++) {
        int bin = b0 + bb;
        unsigned vbase = ((unsigned)bin) << 9;
        unsigned i0 = startS[bin], i1 = startS[bin + 1];
        for (unsigned tb = i0; tb < i1; tb += TILED) {
            unsigned n = (i1 - tb < (unsigned)TILED) ? (i1 - tb) : (unsigned)TILED;
            th[t] = 0u;
            __syncthreads();
            // A: tile histogram by dst-bin
            for (unsigned i = t; i < n; i += 1024)
                atomicAdd(&th[(ebufB[tb + i].x & 0x7FFFFu) >> DSH], 1u);
            __syncthreads();
            // B: exclusive scan over 1024 bins
            unsigned own = th[t];
            sc[t] = own;
            __syncthreads();
            for (int off = 1; off < 1024; off <<= 1) {
                unsigned u = (t >= off) ? sc[t - off] : 0u;
                __syncthreads();
                sc[t] += u;
                __syncthreads();
            }
            unsigned ex = sc[t] - own;
            th[t] = ex; tf[t] = ex;
            __syncthreads();
            // C: LDS scatter (tile re-read is L1/L2-hot; vcx segment L1-hot)
            for (unsigned i = t; i < n; i += 1024) {
                uint2 kv = ebufB[tb + i];
                unsigned d = kv.x & 0x7FFFFu;
                float4 g = vcx[vbase | (kv.x >> 19)];
                unsigned p = atomicAdd(&tf[d >> DSH], 1u);
                buf[p] = make_uint4(d & (CPB - 1u),
                                    __float_as_uint(__uint_as_float(kv.y) * g.z),
                                    __float_as_uint(g.x), __float_as_uint(g.y));
            }
            __syncthreads();
            // D: per-bin coalesced run write-out
            int w = t >> 6, ln = t & 63;
            for (int b = w; b < NBD; b += 16) {
                unsigned lo = th[b], cnt = tf[b] - lo, gb = cur[b];
                for (unsigned j = ln; j < cnt; j += 64)
                    if (gb + j < cap) ebufD[gb + j] = buf[lo + j];
            }
            __syncthreads();
            cur[t] += tf[t] - th[t];
            __syncthreads();
        }
    }
}

// ---- (legacy) D scatter from original arrays: ILP-4 vcx gather ----
__global__ __launch_bounds__(1024) void k_scatD(const int* __restrict__ src, const int* __restrict__ dst,
                                                const float* __restrict__ A,
                                                const unsigned* __restrict__ offs,
                                                const float4* __restrict__ vcx,
                                                uint4* __restrict__ ebufD,
                                                long long s_begin, long long s_end, int per) {
    __shared__ unsigned cur[NBINS];
    int t = threadIdx.x, sl = blockIdx.x;
    const unsigned* o = offs + (size_t)sl * NBINS;
    for (int b = t; b < NBINS; b += 1024) cur[b] = o[b];
    __syncthreads();
    long long s0 = s_begin + (long long)sl * per;
    long long s1 = s0 + per; if (s1 > s_end) s1 = s_end;
    for (long long i = s0 + t; i < s1; i += 4096) {
        unsigned sv[4], dv[4]; float av[4]; bool hv[4];
#pragma unroll
        for (int j = 0; j < 4; j++) {
            long long idx = i + (long long)j * 1024;
            hv[j] = idx < s1;
            if (hv[j]) { sv[j] = (unsigned)src[idx]; dv[j] = (unsigned)dst[idx]; av[j] = A[idx]; }
            else       { sv[j] = 0u; dv[j] = 0u; av[j] = 0.0f; }
        }
        float4 g[4];
#pragma unroll
        for (int j = 0; j < 4; j++)
            if (hv[j]) g[j] = vcx[sv[j]];
#pragma unroll
        for (int j = 0; j < 4; j++) {
            if (!hv[j]) continue;
            unsigned pos = atomicAdd(&cur[dv[j] >> DSH], 1u);
            ebufD[pos] = make_uint4(dv[j] & (CPB - 1u), __float_as_uint(av[j] * g[j].z),
                                    __float_as_uint(g[j].x), __float_as_uint(g[j].y));
        }
    }
}

// ---- v2c aggregate (512-con bins): streaming; embed on the fly; LDS acc ----
__global__ __launch_bounds__(256) void k_aggD(
        const uint4* __restrict__ ebufD, const unsigned* __restrict__ startD,
        const float* __restrict__ Wv, const float* __restrict__ bv,
        float* __restrict__ bufC, float* __restrict__ deg_c, int NC) {
    __shared__ float acc[CPB * HF];
    __shared__ unsigned cnt[CPB];
    int t = threadIdx.x, b = blockIdx.x;
    for (int i = t; i < CPB * HF; i += 256) acc[i] = 0.0f;
    cnt[t] = 0u; cnt[t + 256] = 0u;
    float wv0[HF], wv1[HF], bvv[HF];
#pragma unroll
    for (int h = 0; h < HF; h++) { wv0[h] = Wv[h]; wv1[h] = Wv[HF + h]; bvv[h] = bv[h]; }
    __syncthreads();
    unsigned i0 = startD[b], i1 = startD[b + 1];
    for (unsigned i = i0 + t; i < i1; i += 256) {
        uint4 kv = ebufD[i];
        unsigned dl = kv.x;
        float anv = __uint_as_float(kv.y);
        float c   = __uint_as_float(kv.z);
        float x   = __uint_as_float(kv.w);
        float* ac = acc + dl * HF;
#pragma unroll
        for (int h = 0; h < HF; h++) {
            float e = fmaxf(fmaf(c, wv0[h], fmaf(x, wv1[h], bvv[h])), 0.0f);
            atomicAdd(ac + h, anv * e);
        }
        atomicAdd(&cnt[dl], 1u);
    }
    __syncthreads();
#pragma unroll
    for (int k = 0; k < 2; k++) {
        int gid = b * CPB + k * 256 + t;
        if (gid < NC) {
            float* row = bufC + (size_t)gid * BST;
#pragma unroll
            for (int h = 0; h < HF; h++) row[h] += acc[(k * 256 + t) * HF + h];
            deg_c[gid] += (float)cnt[k * 256 + t];
        }
    }
}

// ---- con transform in place (padded rows): y = relu((row@W2)*nc + b2)*nc ----
__global__ void k_conT(float* __restrict__ bufC, const float* __restrict__ deg_c,
                       const float* __restrict__ W2, const float* __restrict__ b2, int NC) {
    __shared__ float sW[HF * HF], sb[HF];
    int t = threadIdx.x;
    if (t < HF * HF) sW[t] = W2[t];
    if (t < HF)      sb[t] = b2[t];
    __syncthreads();
    int i = blockIdx.x * 256 + t;
    if (i >= NC) return;
    float nc = rsqrtf(fmaxf(deg_c[i], 1.0f));
    float* row = bufC + (size_t)i * BST;
    float x[HF];
#pragma unroll
    for (int h = 0; h < HF; h++) x[h] = row[h];
#pragma unroll
    for (int j = 0; j < HF; j++) {
        float a = 0.0f;
#pragma unroll
        for (int k = 0; k < HF; k++) a = fmaf(x[k], sW[k * HF + j], a);
        row[j] = fmaxf(fmaf(a, nc, sb[j]), 0.0f) * nc;
    }
}

// ---- fused c2v aggregate + @W2 + norm + MLP + mean (512-var bins).
// Cooperative gather: 4 lanes per edge, one 64-B line request per edge.
// Structurally at the ~1 req/cy/XCD L2 wall (~833 us @16M edges). ----
__global__ __launch_bounds__(256) void k_aggS(
        const uint2* __restrict__ ebufS, const unsigned* __restrict__ startS,
        const float* __restrict__ bufC, const float4* __restrict__ vcx,
        const float* __restrict__ W2, const float* __restrict__ b2,
        const float* __restrict__ Wo1, const float* __restrict__ bo1,
        const float* __restrict__ Wo2, const float* __restrict__ bo2,
        const float* __restrict__ Wo3, const float* __restrict__ bo3,
        double* __restrict__ gacc, int NV) {
    __shared__ float acc[VPB * HF];
    __shared__ float sW2[HF * HF], sb2[HF], sW1[HF * HF], sb1[HF], sWm[HF * HF], sbm[HF], sW3[HF];
    __shared__ float sb3;
    __shared__ double red[256];
    int t = threadIdx.x, b = blockIdx.x;
    for (int i = t; i < VPB * HF; i += 256) acc[i] = 0.0f;
    if (t < HF * HF) { sW2[t] = W2[t]; sW1[t] = Wo1[t]; sWm[t] = Wo2[t]; }
    if (t < HF)      { sb2[t] = b2[t]; sb1[t] = bo1[t]; sbm[t] = bo2[t]; sW3[t] = Wo3[t]; }
    if (t == 0)      sb3 = bo3[0];
    __syncthreads();
    unsigned i0 = startS[b], i1 = startS[b + 1];
    int grp = t >> 2;          // 64 edge-groups per block iteration
    int q   = t & 3;           // quarter of the 64-B row
    int nq  = (q < 2) ? 4 : (q == 2 ? 2 : 0);
    for (unsigned base = i0; base < i1; base += 64) {
        unsigned e = base + (unsigned)grp;
        bool ok = e < i1;
        uint2 kv = ok ? ebufS[e] : make_uint2(0u, 0u);
        float4 y = make_float4(0.f, 0.f, 0.f, 0.f);
        if (ok) y = *(const float4*)(bufC + (size_t)(kv.x & 0x7FFFFu) * BST + 4 * q);
        if (ok && nq) {
            float a = __uint_as_float(kv.y);
            float* ac = acc + (kv.x >> 19) * HF + 4 * q;
            atomicAdd(ac + 0, a * y.x);
            atomicAdd(ac + 1, a * y.y);
            if (nq == 4) {
                atomicAdd(ac + 2, a * y.z);
                atomicAdd(ac + 3, a * y.w);
            }
        }
    }
    __syncthreads();
    double local = 0.0;
#pragma unroll
    for (int k = 0; k < 2; k++) {
        int v = b * VPB + k * 256 + t;
        if (v < NV) {
            float nv = vcx[v].z;
            float x[HF], hvv[HF], h1[HF], h2[HF];
#pragma unroll
            for (int h = 0; h < HF; h++) x[h] = acc[(k * 256 + t) * HF + h];
#pragma unroll
            for (int j = 0; j < HF; j++) {
                float a = 0.0f;
#pragma unroll
                for (int kk = 0; kk < HF; kk++) a = fmaf(x[kk], sW2[kk * HF + j], a);
                hvv[j] = fmaxf(fmaf(a, nv, sb2[j]), 0.0f);
            }
#pragma unroll
            for (int j = 0; j < HF; j++) {
                float a = sb1[j];
#pragma unroll
                for (int kk = 0; kk < HF; kk++) a = fmaf(hvv[kk], sW1[kk * HF + j], a);
                h1[j] = fmaxf(a, 0.0f);
            }
#pragma unroll
            for (int j = 0; j < HF; j++) {
                float a = sbm[j];
#pragma unroll
                for (int kk = 0; kk < HF; kk++) a = fmaf(h1[kk], sWm[kk * HF + j], a);
                h2[j] = fmaxf(a, 0.0f);
            }
            float logit = sb3;
#pragma unroll
            for (int kk = 0; kk < HF; kk++) logit = fmaf(h2[kk], sW3[kk], logit);
            local += (double)logit;
        }
    }
    red[t] = local;
    __syncthreads();
    for (int s = 128; s > 0; s >>= 1) {
        if (t < s) red[t] += red[t + s];
        __syncthreads();
    }
    if (t == 0) atomicAdd(gacc, red[0]);
}

__global__ void k_out(const double* __restrict__ acc, float* __restrict__ out, int NV) {
    out[0] = (float)(acc[0] / (double)NV);
}

// ============================================================================
// FALLBACK PATH (round-1, known-good, ~102 MB ws): global-atomic scatter.
// ============================================================================

__global__ void k_degree(const int* __restrict__ src, const int* __restrict__ dst,
                         float* __restrict__ deg_v, float* __restrict__ deg_c, int E) {
    int i = blockIdx.x * blockDim.x + threadIdx.x;
    if (i < E) {
        atomicAdd(&deg_v[src[i]], 1.0f);
        atomicAdd(&deg_c[dst[i]], 1.0f);
    }
}

__global__ void k_norm(float* __restrict__ d, int n) {
    int i = blockIdx.x * blockDim.x + threadIdx.x;
    if (i < n) d[i] = 1.0f / sqrtf(fmaxf(d[i], 1.0f));
}

__global__ void k_var_emb(const float* __restrict__ var_c, const float* __restrict__ var_x,
                          const float* __restrict__ norm_v,
                          const float* __restrict__ Wv, const float* __restrict__ bv,
                          const float* __restrict__ W2,
                          float* __restrict__ out, int NV) {
    __shared__ float sWv[2 * HF], sbv[HF], sW2[HF * HF];
    int t = threadIdx.x;
    if (t < 2 * HF) sWv[t] = Wv[t];
    if (t < HF)     sbv[t] = bv[t];
    if (t < HF * HF) sW2[t] = W2[t];
    __syncthreads();
    int i = blockIdx.x * blockDim.x + t;
    if (i >= NV) return;
    float c = var_c[i], x = var_x[i], nv = norm_v[i];
    float e[HF];
#pragma unroll
    for (int h = 0; h < HF; h++)
        e[h] = fmaxf(fmaf(c, sWv[h], fmaf(x, sWv[HF + h], sbv[h])), 0.0f) * nv;
    float* row = out + (size_t)i * ST;
#pragma unroll
    for (int j = 0; j < HF; j++) {
        float acc = 0.0f;
#pragma unroll
        for (int k = 0; k < HF; k++) acc = fmaf(e[k], sW2[k * HF + j], acc);
        row[j] = acc;
    }
}

__global__ void k_edge(const int* __restrict__ gidx, const int* __restrict__ didx,
                       const float* __restrict__ A,
                       const float* __restrict__ h, float* __restrict__ agg, int E) {
    int tid = blockIdx.x * blockDim.x + threadIdx.x;
    int e = tid / 5;
    if (e >= E) return;
    int q = tid - e * 5;
    int s = gidx[e], d = didx[e];
    float a = A[e];
    const float2 m = *(const float2*)(h + (size_t)s * ST + 2 * q);
    float* o = agg + (size_t)d * ST + 2 * q;
    atomicAdd(o,     m.x * a);
    atomicAdd(o + 1, m.y * a);
}

__global__ void k_con(float* __restrict__ buf, const float* __restrict__ norm_c,
                      const float* __restrict__ W2, const float* __restrict__ b2, int NC) {
    __shared__ float sW2[HF * HF], sb2[HF];
    int t = threadIdx.x;
    if (t < HF * HF) sW2[t] = W2[t];
    if (t < HF)      sb2[t] = b2[t];
    __syncthreads();
    int i = blockIdx.x * blockDim.x + t;
    if (i >= NC) return;
    float nc = norm_c[i];
    float* row = buf + (size_t)i * ST;
    float hc[HF];
#pragma unroll
    for (int h = 0; h < HF; h++)
        hc[h] = fmaxf(fmaf(row[h], nc, sb2[h]), 0.0f) * nc;
#pragma unroll
    for (int j = 0; j < HF; j++) {
        float acc = 0.0f;
#pragma unroll
        for (int k = 0; k < HF; k++) acc = fmaf(hc[k], sW2[k * HF + j], acc);
        row[j] = acc;
    }
}

__global__ void k_final(const float* __restrict__ agg_v, const float* __restrict__ norm_v,
                        const float* __restrict__ b2,
                        const float* __restrict__ Wo1, const float* __restrict__ bo1,
                        const float* __restrict__ Wo2, const float* __restrict__ bo2,
                        const float* __restrict__ Wo3, const float* __restrict__ bo3,
                        double* __restrict__ acc, int NV) {
    __shared__ float sb2[HF], sW1[HF * HF], sb1[HF], sW2m[HF * HF], sb2m[HF], sW3[HF];
    __shared__ float sb3;
    __shared__ double red[256];
    int t = threadIdx.x;
    if (t < HF)      sb2[t]  = b2[t];
    if (t < HF * HF) sW1[t]  = Wo1[t];
    if (t < HF)      sb1[t]  = bo1[t];
    if (t < HF * HF) sW2m[t] = Wo2[t];
    if (t < HF)      sb2m[t] = bo2[t];
    if (t < HF)      sW3[t]  = Wo3[t];
    if (t == 0)      sb3     = bo3[0];
    __syncthreads();
    int i = blockIdx.x * blockDim.x + t;
    double local = 0.0;
    if (i < NV) {
        float nv = norm_v[i];
        const float* row = agg_v + (size_t)i * ST;
        float v[HF], h1[HF], h2[HF];
#pragma unroll
        for (int h = 0; h < HF; h++) v[h] = fmaxf(fmaf(row[h], nv, sb2[h]), 0.0f);
#pragma unroll
        for (int j = 0; j < HF; j++) {
            float a = sb1[j];
#pragma unroll
            for (int k = 0; k < HF; k++) a = fmaf(v[k], sW1[k * HF + j], a);
            h1[j] = fmaxf(a, 0.0f);
        }
#pragma unroll
        for (int j = 0; j < HF; j++) {
            float a = sb2m[j];
#pragma unroll
            for (int k = 0; k < HF; k++) a = fmaf(h1[k], sW2m[k * HF + j], a);
            h2[j] = fmaxf(a, 0.0f);
        }
        float logit = sb3;
#pragma unroll
        for (int k = 0; k < HF; k++) logit = fmaf(h2[k], sW3[k], logit);
        local = (double)logit;
    }
    red[t] = local;
    __syncthreads();
    for (int s = 128; s > 0; s >>= 1) {
        if (t < s) red[t] += red[t + s];
        __syncthreads();
    }
    if (t == 0) atomicAdd(acc, red[0]);
}

// ============================================================================

extern "C" void kernel_launch(void* const* d_in, const int* in_sizes, int n_in,
                              void* d_out, int out_size, void* d_ws, size_t ws_size,
                              hipStream_t stream) {
    const float* var_c = (const float*)d_in[0];
    const float* var_x = (const float*)d_in[1];
    const float* A   = (const float*)d_in[3];
    const int*   src = (const int*)d_in[4];
    const int*   dst = (const int*)d_in[5];
    const float* Wv  = (const float*)d_in[6];
    const float* bv  = (const float*)d_in[7];
    const float* W2  = (const float*)d_in[12];
    const float* b2  = (const float*)d_in[13];
    const float* Wo1 = (const float*)d_in[14];
    const float* bo1 = (const float*)d_in[15];
    const float* Wo2 = (const float*)d_in[16];
    const float* bo2 = (const float*)d_in[17];
    const float* Wo3 = (const float*)d_in[18];
    const float* bo3 = (const float*)d_in[19];

    const int NV = in_sizes[0];
    const int NC = in_sizes[2];
    const int E  = in_sizes[3];

    long long EcMaxUsed = 0;
    auto layout_bytes = [&](int nDc, bool binchunk, size_t* offs_out) -> size_t {
        size_t off = 0;
        auto alloc = [&](size_t bytes, int slot) {
            if (offs_out) offs_out[slot] = off;
            off = (off + bytes + 255) & ~(size_t)255;
        };
        long long ec;
        if (binchunk) {
            long long vspan = (long long)(NBINS / nDc) * VPB;
            if (vspan > NV) vspan = NV;
            ec = ((long long)E * vspan) / NV + (long long)E / 64 + 1024;
            if (ec > E) ec = E;
        } else {
            ec = ((long long)E + nDc - 1) / nDc;
        }
        EcMaxUsed = ec;
        alloc((size_t)NC * BST * 4, 0);       // bufC
        alloc((size_t)NV * 16, 1);            // vcx (float4)
        alloc((size_t)NC * 4, 2);             // deg_c
        alloc((size_t)SLC * NBINS * 4, 3);    // hS / offsS
        alloc((size_t)SLC * NBINS * 4, 4);    // hD / offsD (reused per chunk)
        alloc((size_t)NBINS * 4, 5);          // colT
        alloc((size_t)(NBINS + 1) * 4, 6);    // startS
        alloc((size_t)(NBINS + 1) * 4, 7);    // startD
        alloc(8, 8);                          // gacc
        alloc((size_t)E * 8, 9);              // ebufS (persists)
        alloc((size_t)ec * 16, 10);           // ebufD (per chunk)
        return off;
    };

    int nD = 0;
    bool binc = false;
    size_t offs[11];
    for (int cand : {4, 8, 16}) {
        if (layout_bytes(cand, true, nullptr) <= ws_size) { nD = cand; binc = true; break; }
    }
    if (nD == 0) {
        for (int cand = 2; cand <= 16; cand++)
            if (layout_bytes(cand, false, nullptr) <= ws_size) { nD = cand; break; }
    }
    bool fast = (nD > 0) && (NV <= (1 << 20)) && (NC <= (1 << 19)) && (E > 0);

    char* ws = (char*)d_ws;
    if (fast) {
        layout_bytes(nD, binc, offs);
        const long long EcMax = EcMaxUsed;
        float*    bufC   = (float*)(ws + offs[0]);
        float4*   vcx    = (float4*)(ws + offs[1]);
        float*    deg_c  = (float*)(ws + offs[2]);
        unsigned* hS     = (unsigned*)(ws + offs[3]);
        unsigned* hD     = (unsigned*)(ws + offs[4]);
        unsigned* colT   = (unsigned*)(ws + offs[5]);
        unsigned* startS = (unsigned*)(ws + offs[6]);
        unsigned* startD = (unsigned*)(ws + offs[7]);
        double*   gacc   = (double*)(ws + offs[8]);
        uint2*    ebufS  = (uint2*)(ws + offs[9]);
        uint4*    ebufD  = (uint4*)(ws + offs[10]);

        const int perS = (int)(((long long)E + SLC - 1) / SLC);
        const int NB_S = (NV + VPB - 1) / VPB;   // 512-var src bins
        const int NB_C = (NC + 255) >> 8;        // conT blocks (256/blk)
        const int NB_C2 = (NC + CPB - 1) / CPB;  // aggD blocks (512-con bins)

        hipMemsetAsync(bufC,  0, (size_t)NC * BST * 4, stream);
        hipMemsetAsync(deg_c, 0, (size_t)NC * 4, stream);
        hipMemsetAsync(gacc,  0, 8, stream);

        // 1) S-sort by src-bin (tile-sorted coalesced scatter)
        k_hist<<<SLC, 1024, 0, stream>>>(src, hS, 0, E, perS, 9);
        k_coltot<<<NBINS / 256, 256, 0, stream>>>(hS, colT);
        k_prefix<<<1, 1024, 0, stream>>>(colT, startS);
        k_offs<<<NBINS / 256, 256, 0, stream>>>(hS, startS);
        k_scatS2<<<SLC, 1024, 0, stream>>>(src, dst, A, hS, ebufS, E, perS);

        // 2) degrees from sorted keys -> vcx
        k_cntS2<<<NB_S, 256, 0, stream>>>(ebufS, startS, var_c, var_x, vcx, NV);

        // 3) D chunks -> tile-sorted coalesced D scatter -> streaming v2c agg
        if (binc) {
            const int binsChunk = NBINS / nD;
            const int binsPer   = (binsChunk + SLC - 1) / SLC;
            for (int c = 0; c < nD; c++) {
                int B0 = c * binsChunk;
                k_histD2<<<SLC, 1024, 0, stream>>>(ebufS, startS, hD, B0, binsPer);
                k_coltot<<<NBINS / 256, 256, 0, stream>>>(hD, colT);
                k_prefix<<<1, 1024, 0, stream>>>(colT, startD);
                k_offs<<<NBINS / 256, 256, 0, stream>>>(hD, startD);
                k_scatD3<<<SLC, 1024, 0, stream>>>(ebufS, startS, hD, vcx, ebufD,
                                                   B0, binsPer, (unsigned)EcMax);
                k_aggD<<<NB_C2, 256, 0, stream>>>(ebufD, startD, Wv, bv, bufC, deg_c, NC);
            }
        } else {
            const int perD = (int)((EcMax + SLC - 1) / SLC);
            for (int c = 0; c < nD; c++) {
                long long cb = (long long)c * EcMax;
                long long ce = cb + EcMax; if (ce > E) ce = E;
                k_hist<<<SLC, 1024, 0, stream>>>(dst, hD, cb, ce, perD, DSH);
                k_coltot<<<NBINS / 256, 256, 0, stream>>>(hD, colT);
                k_prefix<<<1, 1024, 0, stream>>>(colT, startD);
                k_offs<<<NBINS / 256, 256, 0, stream>>>(hD, startD);
                k_scatD<<<SLC, 1024, 0, stream>>>(src, dst, A, hD, vcx, ebufD, cb, ce, perD);
                k_aggD<<<NB_C2, 256, 0, stream>>>(ebufD, startD, Wv, bv, bufC, deg_c, NC);
            }
        }
        k_conT<<<NB_C, 256, 0, stream>>>(bufC, deg_c, W2, b2, NC);

        // 4) fused c2v aggregate + MLP + mean
        k_aggS<<<NB_S, 256, 0, stream>>>(ebufS, startS, bufC, vcx, W2, b2,
                                         Wo1, bo1, Wo2, bo2, Wo3, bo3, gacc, NV);
        k_out<<<1, 1, 0, stream>>>(gacc, (float*)d_out, NV);
    } else {
        // round-1 fallback
        const int B = 256;
        float* fbufV = (float*)ws;
        float* fbufC = (float*)(ws + (size_t)NV * ST * 4);
        float* deg_v = (float*)(ws + (size_t)(NV + NC) * ST * 4);
        float* deg_c = deg_v + NV;
        size_t acc_off = ((size_t)(NV + NC) * ST * 4 + (size_t)(NV + NC) * 4 + 7) & ~(size_t)7;
        double* acc = (double*)(ws + acc_off);

        hipMemsetAsync(deg_v, 0, (size_t)(NV + NC) * 4, stream);
        hipMemsetAsync(fbufC, 0, (size_t)NC * ST * 4, stream);
        hipMemsetAsync(acc, 0, sizeof(double), stream);

        k_degree<<<(E + B - 1) / B, B, 0, stream>>>(src, dst, deg_v, deg_c, E);
        k_norm<<<(NV + NC + B - 1) / B, B, 0, stream>>>(deg_v, NV + NC);
        k_var_emb<<<(NV + B - 1) / B, B, 0, stream>>>(var_c, var_x, deg_v, Wv, bv, W2, fbufV, NV);

        long long tE = (long long)E * 5;
        k_edge<<<(int)((tE + B - 1) / B), B, 0, stream>>>(src, dst, A, fbufV, fbufC, E);
        k_con<<<(NC + B - 1) / B, B, 0, stream>>>(fbufC, deg_c, W2, b2, NC);

        hipMemsetAsync(fbufV, 0, (size_t)NV * ST * 4, stream);
        k_edge<<<(int)((tE + B - 1) / B), B, 0, stream>>>(dst, src, A, fbufC, fbufV, E);

        k_final<<<(NV + B - 1) / B, B, 0, stream>>>(fbufV, deg_v, b2, Wo1, bo1, Wo2, bo2, Wo3, bo3, acc, NV);
        k_out<<<1, 1, 0, stream>>>(acc, (float*)d_out, NV);
    }
}

// Round 6
// 2476.625 us; speedup vs baseline: 1.0605x; 1.0605x over previous
//
#include <hip/hip_runtime.h>

#define HF 10        // feature width
#define ST 16        // fallback-path row stride
#define BST 16       // bufC padded row stride (64 B -> 1 line per random gather)
#define SLC 256      // scatter/hist slices (WGs)
#define NBINS 2048   // src bins (512 vars/bin); array stride for all hists
#define VPB 512      // vars per src-bin
#define TILE 12288   // scatS2 LDS tile (96 KB buf; total ~124 KB LDS)
#define NBD 512      // dst bins (1024 cons/bin); 489 used at NC=500K
#define DSH 10       // dst shift: 1024 cons per dst-bin
#define CPB 1024     // cons per dst-bin (aggD block width)
#define TILED 7424   // scatD4 tile (116 KB uint4 buf; total ~122 KB LDS)

// ============================================================================
// FAST PATH v7 (request-rate aware; scatD4 repairs v6's regression):
//   Model: random 64-B line requests service at ~1/cy per XCD L2 (16M req =
//   833 us floor, hit/miss-independent; verified r2-r5). k_aggS sits AT that
//   wall structurally. k_scatD2 (v4) was at the same wall via 16M scattered
//   16-B writes. v6's scatD3 fix lost to overhead: 20-barrier scans at
//   1 blk/CU, tail tiles, 6/64-lane write-out. scatD4 fixes all three:
//   wave-level scan (3 barriers), tiles spanning the block's bin range,
//   position-based all-lane write-out, 1024-con dst bins (~240-B runs).
//   1) per-slice src-bin hist -> cursors              [k_hist/coltot/prefix/offs]
//   2) tile-sorted coalesced S scatter                [k_scatS2]
//   3) degrees/norm from sorted keys (streaming)      [k_cntS2]
//   4) D-phase per src-bin range from sorted buffer:
//      tile-sorted coalesced D scatter (vcx L1-hot)   [k_histD2/k_scatD4]
//   5) streaming v2c aggregation (1024-con bins)      [k_aggD]
//   6) con transform                                  [k_conT]
//   7) fused c2v aggregate + @W2 + MLP + mean         [k_aggS]
// ============================================================================

// ---- per-slice histogram of idx>>shift over [s_begin, s_end) ----
__global__ __launch_bounds__(1024) void k_hist(const int* __restrict__ idx,
                                               unsigned* __restrict__ hist,
                                               long long s_begin, long long s_end,
                                               int per, int shift) {
    __shared__ unsigned l[NBINS];
    int t = threadIdx.x, sl = blockIdx.x;
    for (int b = t; b < NBINS; b += 1024) l[b] = 0u;
    __syncthreads();
    long long s0 = s_begin + (long long)sl * per;
    long long s1 = s0 + per; if (s1 > s_end) s1 = s_end;
    for (long long i = s0 + t; i < s1; i += 1024)
        atomicAdd(&l[((unsigned)idx[i]) >> shift], 1u);
    __syncthreads();
    unsigned* out = hist + (size_t)sl * NBINS;
    for (int b = t; b < NBINS; b += 1024) out[b] = l[b];
}

// ---- per-bin totals over slices (coalesced column walk) ----
__global__ void k_coltot(const unsigned* __restrict__ h, unsigned* __restrict__ colT) {
    int b = blockIdx.x * 256 + threadIdx.x;
    unsigned s = 0u;
    for (int sl = 0; sl < SLC; sl++) s += h[(size_t)sl * NBINS + b];
    colT[b] = s;
}

// ---- exclusive prefix over NBINS(2048) bin totals ----
__global__ __launch_bounds__(1024) void k_prefix(const unsigned* __restrict__ colT,
                                                 unsigned* __restrict__ start) {
    __shared__ unsigned p[1024];
    int t = threadIdx.x;
    uint2 v = *(const uint2*)(colT + 2 * t);
    unsigned own = v.x + v.y;
    p[t] = own;
    __syncthreads();
    for (int off = 1; off < 1024; off <<= 1) {
        unsigned u = (t >= off) ? p[t - off] : 0u;
        __syncthreads();
        p[t] += u;
        __syncthreads();
    }
    unsigned e = p[t] - own;
    *(uint2*)(start + 2 * t) = make_uint2(e, e + v.x);
    if (t == 1023) start[NBINS] = p[1023];
}

// ---- per-slice exclusive cursors, written in place over h ----
__global__ void k_offs(unsigned* __restrict__ h, const unsigned* __restrict__ start) {
    int b = blockIdx.x * 256 + threadIdx.x;
    unsigned cur = start[b];
    for (int sl = 0; sl < SLC; sl++) {
        unsigned* cell = h + (size_t)sl * NBINS + b;
        unsigned v = *cell;
        *cell = cur;
        cur += v;
    }
}

// ---- S scatter: LDS tile counting-sort + per-bin coalesced run write-out.
//      key=(slow9<<19)|dst19, payload A. ----
__global__ __launch_bounds__(1024) void k_scatS2(
        const int* __restrict__ src, const int* __restrict__ dst,
        const float* __restrict__ A, const unsigned* __restrict__ offs,
        uint2* __restrict__ ebufS, long long E, int per) {
    __shared__ unsigned cur[NBINS];
    __shared__ unsigned th[NBINS];
    __shared__ unsigned tf[NBINS];
    __shared__ unsigned sc[1024];
    __shared__ __align__(16) uint2 buf[TILE];
    int t = threadIdx.x, sl = blockIdx.x;
    const unsigned* o = offs + (size_t)sl * NBINS;
    for (int b = t; b < NBINS; b += 1024) cur[b] = o[b];
    long long s0 = (long long)sl * per;
    long long s1 = s0 + per; if (s1 > E) s1 = E;
    for (long long tb = s0; tb < s1; tb += TILE) {
        int n = (int)((s1 - tb < (long long)TILE) ? (s1 - tb) : (long long)TILE);
        for (int b = t; b < NBINS; b += 1024) th[b] = 0u;
        __syncthreads();
        for (int i = t; i < n; i += 1024)
            atomicAdd(&th[((unsigned)src[tb + i]) >> 9], 1u);
        __syncthreads();
        unsigned a0 = th[2 * t], a1 = th[2 * t + 1];
        unsigned own = a0 + a1;
        sc[t] = own;
        __syncthreads();
        for (int off = 1; off < 1024; off <<= 1) {
            unsigned u = (t >= off) ? sc[t - off] : 0u;
            __syncthreads();
            sc[t] += u;
            __syncthreads();
        }
        unsigned ex = sc[t] - own;
        th[2 * t] = ex;     th[2 * t + 1] = ex + a0;
        tf[2 * t] = ex;     tf[2 * t + 1] = ex + a0;
        __syncthreads();
        for (int i = t; i < n; i += 1024) {
            unsigned s = (unsigned)src[tb + i], d = (unsigned)dst[tb + i];
            float a = A[tb + i];
            unsigned p = atomicAdd(&tf[s >> 9], 1u);
            buf[p] = make_uint2(((s & 511u) << 19) | d, __float_as_uint(a));
        }
        __syncthreads();
        int w = t >> 6, ln = t & 63;
        for (int b = w; b < NBINS; b += 16) {
            unsigned lo = th[b], cnt = tf[b] - lo, gb = cur[b];
            for (unsigned j = ln; j < cnt; j += 64)
                ebufS[gb + j] = buf[lo + j];
        }
        __syncthreads();
        for (int b = t; b < NBINS; b += 1024) cur[b] += tf[b] - th[b];
        __syncthreads();
    }
}

// ---- degrees from sorted S keys -> vcx[v]=(c,x,rsqrt(max(deg,1)),0) ----
__global__ void k_cntS2(const uint2* __restrict__ ebufS, const unsigned* __restrict__ startS,
                        const float* __restrict__ var_c, const float* __restrict__ var_x,
                        float4* __restrict__ vcx, int NV) {
    __shared__ unsigned cnt[VPB];
    int t = threadIdx.x, b = blockIdx.x;
    cnt[t] = 0u; cnt[t + 256] = 0u;
    __syncthreads();
    unsigned i0 = startS[b], i1 = startS[b + 1];
    for (unsigned i = i0 + t; i < i1; i += 256)
        atomicAdd(&cnt[ebufS[i].x >> 19], 1u);
    __syncthreads();
#pragma unroll
    for (int k = 0; k < 2; k++) {
        int v = b * VPB + k * 256 + t;
        if (v < NV)
            vcx[v] = make_float4(var_c[v], var_x[v],
                                 rsqrtf(fmaxf((float)cnt[k * 256 + t], 1.0f)), 0.0f);
    }
}

// ---- D hist: dst-bin (>>DSH) histogram from the SORTED edge buffer. ----
__global__ __launch_bounds__(1024) void k_histD2(const uint2* __restrict__ ebufB,
                                                 const unsigned* __restrict__ startS,
                                                 unsigned* __restrict__ hist,
                                                 int B0, int binsPer, int binsChunk) {
    __shared__ unsigned l[NBINS];
    int t = threadIdx.x, sl = blockIdx.x;
    for (int b = t; b < NBINS; b += 1024) l[b] = 0u;
    __syncthreads();
    int b0 = B0 + sl * binsPer;
    int bend = b0 + binsPer;
    if (bend > B0 + binsChunk) bend = B0 + binsChunk;
    unsigned i0 = 0u, i1 = 0u;
    if (b0 < bend) { i0 = startS[b0]; i1 = startS[bend]; }
    for (unsigned i = i0 + t; i < i1; i += 1024)
        atomicAdd(&l[(ebufB[i].x & 0x7FFFFu) >> DSH], 1u);
    __syncthreads();
    unsigned* out = hist + (size_t)sl * NBINS;
    for (int b = t; b < NBINS; b += 1024) out[b] = l[b];
}

// ---- v7 D scatter: per-src-bin-range walk (vcx L1-hot), LDS tile counting
//      sort by dst>>DSH with wave-level scan (3 barriers) and position-based
//      all-lane write-out. Record carries FULL 19-bit dst (aggD masks). ----
__global__ __launch_bounds__(1024) void k_scatD4(
        const uint2* __restrict__ ebufB, const unsigned* __restrict__ startS,
        const unsigned* __restrict__ offs, const float4* __restrict__ vcx,
        uint4* __restrict__ ebufD, int B0, int binsPer, int binsChunk, unsigned cap) {
    __shared__ unsigned cur[NBD], th[NBD], tf[NBD];
    __shared__ unsigned ws[16];
    __shared__ unsigned bnd[16];
    __shared__ __align__(16) uint4 buf[TILED];
    int t = threadIdx.x, sl = blockIdx.x;
    int b0 = B0 + sl * binsPer;
    int bend = b0 + binsPer;
    if (bend > B0 + binsChunk) bend = B0 + binsChunk;
    int binsEff = bend - b0;
    if (binsEff <= 0) return;                         // uniform across block
    const unsigned* o = offs + (size_t)sl * NBINS;
    if (t < NBD) cur[t] = o[t];
    if (t <= binsEff) bnd[t] = startS[b0 + t];
    __syncthreads();
    unsigned r0 = bnd[0], r1 = bnd[binsEff];
    for (unsigned tb = r0; tb < r1; tb += TILED) {
        unsigned n = (r1 - tb < (unsigned)TILED) ? (r1 - tb) : (unsigned)TILED;
        if (t < NBD) th[t] = 0u;
        __syncthreads();
        // A: tile histogram by dst-bin
        for (unsigned i = t; i < n; i += 1024)
            atomicAdd(&th[(ebufB[tb + i].x & 0x7FFFFu) >> DSH], 1u);
        __syncthreads();
        // B: exclusive scan over NBD bins (wave-level, 3 barriers)
        unsigned own = (t < NBD) ? th[t] : 0u;
        unsigned v = own;
#pragma unroll
        for (int d = 1; d < 64; d <<= 1) {
            unsigned u = __shfl_up(v, (unsigned)d, 64);
            if ((t & 63) >= d) v += u;
        }
        if ((t & 63) == 63 && t < NBD) ws[t >> 6] = v;
        __syncthreads();
        if (t == 0) {
            unsigned run = 0u;
#pragma unroll
            for (int w = 0; w < NBD / 64; w++) { unsigned x = ws[w]; ws[w] = run; run += x; }
        }
        __syncthreads();
        if (t < NBD) { unsigned ex = v - own + ws[t >> 6]; th[t] = ex; tf[t] = ex; }
        __syncthreads();
        // C: LDS scatter (src-bin via boundary compare; vcx segment L1-hot)
        for (unsigned i = t; i < n; i += 1024) {
            unsigned gi = tb + i;
            uint2 kv = ebufB[gi];
            unsigned d = kv.x & 0x7FFFFu;
            unsigned sb = 0u;
            for (int j = 1; j < binsEff; j++) sb += (gi >= bnd[j]) ? 1u : 0u;
            float4 g = vcx[(((unsigned)b0 + sb) << 9) | (kv.x >> 19)];
            unsigned p = atomicAdd(&tf[d >> DSH], 1u);
            buf[p] = make_uint4(d, __float_as_uint(__uint_as_float(kv.y) * g.z),
                                __float_as_uint(g.x), __float_as_uint(g.y));
        }
        __syncthreads();
        // D: position-based write-out — ALL lanes active, runs contiguous
        for (unsigned p = t; p < n; p += 1024) {
            uint4 rec = buf[p];
            unsigned b = rec.x >> DSH;
            unsigned pos = cur[b] + (p - th[b]);
            if (pos < cap) ebufD[pos] = rec;
        }
        __syncthreads();
        if (t < NBD) cur[t] += tf[t] - th[t];
        __syncthreads();
    }
}

// ---- (legacy) D scatter from original arrays: ILP-4 vcx gather ----
__global__ __launch_bounds__(1024) void k_scatD(const int* __restrict__ src, const int* __restrict__ dst,
                                                const float* __restrict__ A,
                                                const unsigned* __restrict__ offs,
                                                const float4* __restrict__ vcx,
                                                uint4* __restrict__ ebufD,
                                                long long s_begin, long long s_end, int per) {
    __shared__ unsigned cur[NBINS];
    int t = threadIdx.x, sl = blockIdx.x;
    const unsigned* o = offs + (size_t)sl * NBINS;
    for (int b = t; b < NBINS; b += 1024) cur[b] = o[b];
    __syncthreads();
    long long s0 = s_begin + (long long)sl * per;
    long long s1 = s0 + per; if (s1 > s_end) s1 = s_end;
    for (long long i = s0 + t; i < s1; i += 4096) {
        unsigned sv[4], dv[4]; float av[4]; bool hv[4];
#pragma unroll
        for (int j = 0; j < 4; j++) {
            long long idx = i + (long long)j * 1024;
            hv[j] = idx < s1;
            if (hv[j]) { sv[j] = (unsigned)src[idx]; dv[j] = (unsigned)dst[idx]; av[j] = A[idx]; }
            else       { sv[j] = 0u; dv[j] = 0u; av[j] = 0.0f; }
        }
        float4 g[4];
#pragma unroll
        for (int j = 0; j < 4; j++)
            if (hv[j]) g[j] = vcx[sv[j]];
#pragma unroll
        for (int j = 0; j < 4; j++) {
            if (!hv[j]) continue;
            unsigned pos = atomicAdd(&cur[dv[j] >> DSH], 1u);
            ebufD[pos] = make_uint4(dv[j], __float_as_uint(av[j] * g[j].z),
                                    __float_as_uint(g[j].x), __float_as_uint(g[j].y));
        }
    }
}

// ---- v2c aggregate (1024-con bins): streaming; embed on the fly; LDS acc ----
__global__ __launch_bounds__(256) void k_aggD(
        const uint4* __restrict__ ebufD, const unsigned* __restrict__ startD,
        const float* __restrict__ Wv, const float* __restrict__ bv,
        float* __restrict__ bufC, float* __restrict__ deg_c, int NC) {
    __shared__ float acc[CPB * HF];
    __shared__ unsigned cnt[CPB];
    int t = threadIdx.x, b = blockIdx.x;
    unsigned i0 = startD[b], i1 = startD[b + 1];
    if (i0 >= i1) return;                  // empty bin: nothing to add
    for (int i = t; i < CPB * HF; i += 256) acc[i] = 0.0f;
#pragma unroll
    for (int k = 0; k < CPB / 256; k++) cnt[k * 256 + t] = 0u;
    float wv0[HF], wv1[HF], bvv[HF];
#pragma unroll
    for (int h = 0; h < HF; h++) { wv0[h] = Wv[h]; wv1[h] = Wv[HF + h]; bvv[h] = bv[h]; }
    __syncthreads();
    for (unsigned i = i0 + t; i < i1; i += 256) {
        uint4 kv = ebufD[i];
        unsigned dl = kv.x & (CPB - 1u);
        float anv = __uint_as_float(kv.y);
        float c   = __uint_as_float(kv.z);
        float x   = __uint_as_float(kv.w);
        float* ac = acc + dl * HF;
#pragma unroll
        for (int h = 0; h < HF; h++) {
            float e = fmaxf(fmaf(c, wv0[h], fmaf(x, wv1[h], bvv[h])), 0.0f);
            atomicAdd(ac + h, anv * e);
        }
        atomicAdd(&cnt[dl], 1u);
    }
    __syncthreads();
#pragma unroll
    for (int k = 0; k < CPB / 256; k++) {
        int gid = b * CPB + k * 256 + t;
        if (gid < NC) {
            float* row = bufC + (size_t)gid * BST;
#pragma unroll
            for (int h = 0; h < HF; h++) row[h] += acc[(k * 256 + t) * HF + h];
            deg_c[gid] += (float)cnt[k * 256 + t];
        }
    }
}

// ---- con transform in place (padded rows): y = relu((row@W2)*nc + b2)*nc ----
__global__ void k_conT(float* __restrict__ bufC, const float* __restrict__ deg_c,
                       const float* __restrict__ W2, const float* __restrict__ b2, int NC) {
    __shared__ float sW[HF * HF], sb[HF];
    int t = threadIdx.x;
    if (t < HF * HF) sW[t] = W2[t];
    if (t < HF)      sb[t] = b2[t];
    __syncthreads();
    int i = blockIdx.x * 256 + t;
    if (i >= NC) return;
    float nc = rsqrtf(fmaxf(deg_c[i], 1.0f));
    float* row = bufC + (size_t)i * BST;
    float x[HF];
#pragma unroll
    for (int h = 0; h < HF; h++) x[h] = row[h];
#pragma unroll
    for (int j = 0; j < HF; j++) {
        float a = 0.0f;
#pragma unroll
        for (int k = 0; k < HF; k++) a = fmaf(x[k], sW[k * HF + j], a);
        row[j] = fmaxf(fmaf(a, nc, sb[j]), 0.0f) * nc;
    }
}

// ---- fused c2v aggregate + @W2 + norm + MLP + mean (512-var bins).
// Cooperative gather: 4 lanes per edge, one 64-B line request per edge.
// Structurally at the ~1 req/cy/XCD L2 wall (~833 us @16M edges). ----
__global__ __launch_bounds__(256) void k_aggS(
        const uint2* __restrict__ ebufS, const unsigned* __restrict__ startS,
        const float* __restrict__ bufC, const float4* __restrict__ vcx,
        const float* __restrict__ W2, const float* __restrict__ b2,
        const float* __restrict__ Wo1, const float* __restrict__ bo1,
        const float* __restrict__ Wo2, const float* __restrict__ bo2,
        const float* __restrict__ Wo3, const float* __restrict__ bo3,
        double* __restrict__ gacc, int NV) {
    __shared__ float acc[VPB * HF];
    __shared__ float sW2[HF * HF], sb2[HF], sW1[HF * HF], sb1[HF], sWm[HF * HF], sbm[HF], sW3[HF];
    __shared__ float sb3;
    __shared__ double red[256];
    int t = threadIdx.x, b = blockIdx.x;
    for (int i = t; i < VPB * HF; i += 256) acc[i] = 0.0f;
    if (t < HF * HF) { sW2[t] = W2[t]; sW1[t] = Wo1[t]; sWm[t] = Wo2[t]; }
    if (t < HF)      { sb2[t] = b2[t]; sb1[t] = bo1[t]; sbm[t] = bo2[t]; sW3[t] = Wo3[t]; }
    if (t == 0)      sb3 = bo3[0];
    __syncthreads();
    unsigned i0 = startS[b], i1 = startS[b + 1];
    int grp = t >> 2;          // 64 edge-groups per block iteration
    int q   = t & 3;           // quarter of the 64-B row
    int nq  = (q < 2) ? 4 : (q == 2 ? 2 : 0);
    for (unsigned base = i0; base < i1; base += 64) {
        unsigned e = base + (unsigned)grp;
        bool ok = e < i1;
        uint2 kv = ok ? ebufS[e] : make_uint2(0u, 0u);
        float4 y = make_float4(0.f, 0.f, 0.f, 0.f);
        if (ok) y = *(const float4*)(bufC + (size_t)(kv.x & 0x7FFFFu) * BST + 4 * q);
        if (ok && nq) {
            float a = __uint_as_float(kv.y);
            float* ac = acc + (kv.x >> 19) * HF + 4 * q;
            atomicAdd(ac + 0, a * y.x);
            atomicAdd(ac + 1, a * y.y);
            if (nq == 4) {
                atomicAdd(ac + 2, a * y.z);
                atomicAdd(ac + 3, a * y.w);
            }
        }
    }
    __syncthreads();
    double local = 0.0;
#pragma unroll
    for (int k = 0; k < 2; k++) {
        int v = b * VPB + k * 256 + t;
        if (v < NV) {
            float nv = vcx[v].z;
            float x[HF], hvv[HF], h1[HF], h2[HF];
#pragma unroll
            for (int h = 0; h < HF; h++) x[h] = acc[(k * 256 + t) * HF + h];
#pragma unroll
            for (int j = 0; j < HF; j++) {
                float a = 0.0f;
#pragma unroll
                for (int kk = 0; kk < HF; kk++) a = fmaf(x[kk], sW2[kk * HF + j], a);
                hvv[j] = fmaxf(fmaf(a, nv, sb2[j]), 0.0f);
            }
#pragma unroll
            for (int j = 0; j < HF; j++) {
                float a = sb1[j];
#pragma unroll
                for (int kk = 0; kk < HF; kk++) a = fmaf(hvv[kk], sW1[kk * HF + j], a);
                h1[j] = fmaxf(a, 0.0f);
            }
#pragma unroll
            for (int j = 0; j < HF; j++) {
                float a = sbm[j];
#pragma unroll
                for (int kk = 0; kk < HF; kk++) a = fmaf(h1[kk], sWm[kk * HF + j], a);
                h2[j] = fmaxf(a, 0.0f);
            }
            float logit = sb3;
#pragma unroll
            for (int kk = 0; kk < HF; kk++) logit = fmaf(h2[kk], sW3[kk], logit);
            local += (double)logit;
        }
    }
    red[t] = local;
    __syncthreads();
    for (int s = 128; s > 0; s >>= 1) {
        if (t < s) red[t] += red[t + s];
        __syncthreads();
    }
    if (t == 0) atomicAdd(gacc, red[0]);
}

__global__ void k_out(const double* __restrict__ acc, float* __restrict__ out, int NV) {
    out[0] = (float)(acc[0] / (double)NV);
}

// ============================================================================
// FALLBACK PATH (round-1, known-good, ~102 MB ws): global-atomic scatter.
// ============================================================================

__global__ void k_degree(const int* __restrict__ src, const int* __restrict__ dst,
                         float* __restrict__ deg_v, float* __restrict__ deg_c, int E) {
    int i = blockIdx.x * blockDim.x + threadIdx.x;
    if (i < E) {
        atomicAdd(&deg_v[src[i]], 1.0f);
        atomicAdd(&deg_c[dst[i]], 1.0f);
    }
}

__global__ void k_norm(float* __restrict__ d, int n) {
    int i = blockIdx.x * blockDim.x + threadIdx.x;
    if (i < n) d[i] = 1.0f / sqrtf(fmaxf(d[i], 1.0f));
}

__global__ void k_var_emb(const float* __restrict__ var_c, const float* __restrict__ var_x,
                          const float* __restrict__ norm_v,
                          const float* __restrict__ Wv, const float* __restrict__ bv,
                          const float* __restrict__ W2,
                          float* __restrict__ out, int NV) {
    __shared__ float sWv[2 * HF], sbv[HF], sW2[HF * HF];
    int t = threadIdx.x;
    if (t < 2 * HF) sWv[t] = Wv[t];
    if (t < HF)     sbv[t] = bv[t];
    if (t < HF * HF) sW2[t] = W2[t];
    __syncthreads();
    int i = blockIdx.x * blockDim.x + t;
    if (i >= NV) return;
    float c = var_c[i], x = var_x[i], nv = norm_v[i];
    float e[HF];
#pragma unroll
    for (int h = 0; h < HF; h++)
        e[h] = fmaxf(fmaf(c, sWv[h], fmaf(x, sWv[HF + h], sbv[h])), 0.0f) * nv;
    float* row = out + (size_t)i * ST;
#pragma unroll
    for (int j = 0; j < HF; j++) {
        float acc = 0.0f;
#pragma unroll
        for (int k = 0; k < HF; k++) acc = fmaf(e[k], sW2[k * HF + j], acc);
        row[j] = acc;
    }
}

__global__ void k_edge(const int* __restrict__ gidx, const int* __restrict__ didx,
                       const float* __restrict__ A,
                       const float* __restrict__ h, float* __restrict__ agg, int E) {
    int tid = blockIdx.x * blockDim.x + threadIdx.x;
    int e = tid / 5;
    if (e >= E) return;
    int q = tid - e * 5;
    int s = gidx[e], d = didx[e];
    float a = A[e];
    const float2 m = *(const float2*)(h + (size_t)s * ST + 2 * q);
    float* o = agg + (size_t)d * ST + 2 * q;
    atomicAdd(o,     m.x * a);
    atomicAdd(o + 1, m.y * a);
}

__global__ void k_con(float* __restrict__ buf, const float* __restrict__ norm_c,
                      const float* __restrict__ W2, const float* __restrict__ b2, int NC) {
    __shared__ float sW2[HF * HF], sb2[HF];
    int t = threadIdx.x;
    if (t < HF * HF) sW2[t] = W2[t];
    if (t < HF)      sb2[t] = b2[t];
    __syncthreads();
    int i = blockIdx.x * blockDim.x + t;
    if (i >= NC) return;
    float nc = norm_c[i];
    float* row = buf + (size_t)i * ST;
    float hc[HF];
#pragma unroll
    for (int h = 0; h < HF; h++)
        hc[h] = fmaxf(fmaf(row[h], nc, sb2[h]), 0.0f) * nc;
#pragma unroll
    for (int j = 0; j < HF; j++) {
        float acc = 0.0f;
#pragma unroll
        for (int k = 0; k < HF; k++) acc = fmaf(hc[k], sW2[k * HF + j], acc);
        row[j] = acc;
    }
}

__global__ void k_final(const float* __restrict__ agg_v, const float* __restrict__ norm_v,
                        const float* __restrict__ b2,
                        const float* __restrict__ Wo1, const float* __restrict__ bo1,
                        const float* __restrict__ Wo2, const float* __restrict__ bo2,
                        const float* __restrict__ Wo3, const float* __restrict__ bo3,
                        double* __restrict__ acc, int NV) {
    __shared__ float sb2[HF], sW1[HF * HF], sb1[HF], sW2m[HF * HF], sb2m[HF], sW3[HF];
    __shared__ float sb3;
    __shared__ double red[256];
    int t = threadIdx.x;
    if (t < HF)      sb2[t]  = b2[t];
    if (t < HF * HF) sW1[t]  = Wo1[t];
    if (t < HF)      sb1[t]  = bo1[t];
    if (t < HF * HF) sW2m[t] = Wo2[t];
    if (t < HF)      sb2m[t] = bo2[t];
    if (t < HF)      sW3[t]  = Wo3[t];
    if (t == 0)      sb3     = bo3[0];
    __syncthreads();
    int i = blockIdx.x * blockDim.x + t;
    double local = 0.0;
    if (i < NV) {
        float nv = norm_v[i];
        const float* row = agg_v + (size_t)i * ST;
        float v[HF], h1[HF], h2[HF];
#pragma unroll
        for (int h = 0; h < HF; h++) v[h] = fmaxf(fmaf(row[h], nv, sb2[h]), 0.0f);
#pragma unroll
        for (int j = 0; j < HF; j++) {
            float a = sb1[j];
#pragma unroll
            for (int k = 0; k < HF; k++) a = fmaf(v[k], sW1[k * HF + j], a);
            h1[j] = fmaxf(a, 0.0f);
        }
#pragma unroll
        for (int j = 0; j < HF; j++) {
            float a = sb2m[j];
#pragma unroll
            for (int k = 0; k < HF; k++) a = fmaf(h1[k], sW2m[k * HF + j], a);
            h2[j] = fmaxf(a, 0.0f);
        }
        float logit = sb3;
#pragma unroll
        for (int k = 0; k < HF; k++) logit = fmaf(h2[k], sW3[k], logit);
        local = (double)logit;
    }
    red[t] = local;
    __syncthreads();
    for (int s = 128; s > 0; s >>= 1) {
        if (t < s) red[t] += red[t + s];
        __syncthreads();
    }
    if (t == 0) atomicAdd(acc, red[0]);
}

// ============================================================================

extern "C" void kernel_launch(void* const* d_in, const int* in_sizes, int n_in,
                              void* d_out, int out_size, void* d_ws, size_t ws_size,
                              hipStream_t stream) {
    const float* var_c = (const float*)d_in[0];
    const float* var_x = (const float*)d_in[1];
    const float* A   = (const float*)d_in[3];
    const int*   src = (const int*)d_in[4];
    const int*   dst = (const int*)d_in[5];
    const float* Wv  = (const float*)d_in[6];
    const float* bv  = (const float*)d_in[7];
    const float* W2  = (const float*)d_in[12];
    const float* b2  = (const float*)d_in[13];
    const float* Wo1 = (const float*)d_in[14];
    const float* bo1 = (const float*)d_in[15];
    const float* Wo2 = (const float*)d_in[16];
    const float* bo2 = (const float*)d_in[17];
    const float* Wo3 = (const float*)d_in[18];
    const float* bo3 = (const float*)d_in[19];

    const int NV = in_sizes[0];
    const int NC = in_sizes[2];
    const int E  = in_sizes[3];

    long long EcMaxUsed = 0;
    auto layout_bytes = [&](int nDc, bool binchunk, size_t* offs_out) -> size_t {
        size_t off = 0;
        auto alloc = [&](size_t bytes, int slot) {
            if (offs_out) offs_out[slot] = off;
            off = (off + bytes + 255) & ~(size_t)255;
        };
        long long ec;
        if (binchunk) {
            long long vspan = (long long)(NBINS / nDc) * VPB;
            if (vspan > NV) vspan = NV;
            ec = ((long long)E * vspan) / NV + (long long)E / 64 + 1024;
            if (ec > E) ec = E;
        } else {
            ec = ((long long)E + nDc - 1) / nDc;
        }
        EcMaxUsed = ec;
        alloc((size_t)NC * BST * 4, 0);       // bufC
        alloc((size_t)NV * 16, 1);            // vcx (float4)
        alloc((size_t)NC * 4, 2);             // deg_c
        alloc((size_t)SLC * NBINS * 4, 3);    // hS / offsS
        alloc((size_t)SLC * NBINS * 4, 4);    // hD / offsD (reused per chunk)
        alloc((size_t)NBINS * 4, 5);          // colT
        alloc((size_t)(NBINS + 1) * 4, 6);    // startS
        alloc((size_t)(NBINS + 1) * 4, 7);    // startD
        alloc(8, 8);                          // gacc
        alloc((size_t)E * 8, 9);              // ebufS (persists)
        alloc((size_t)ec * 16, 10);           // ebufD (per chunk)
        return off;
    };

    int nD = 0;
    bool binc = false;
    size_t offs[11];
    for (int cand : {4, 8, 16}) {
        if (layout_bytes(cand, true, nullptr) <= ws_size) { nD = cand; binc = true; break; }
    }
    if (nD == 0) {
        for (int cand = 2; cand <= 16; cand++)
            if (layout_bytes(cand, false, nullptr) <= ws_size) { nD = cand; break; }
    }
    bool fast = (nD > 0) && (NV <= (1 << 20)) && (NC <= (1 << 19)) && (E > 0);

    char* ws = (char*)d_ws;
    if (fast) {
        layout_bytes(nD, binc, offs);
        const long long EcMax = EcMaxUsed;
        float*    bufC   = (float*)(ws + offs[0]);
        float4*   vcx    = (float4*)(ws + offs[1]);
        float*    deg_c  = (float*)(ws + offs[2]);
        unsigned* hS     = (unsigned*)(ws + offs[3]);
        unsigned* hD     = (unsigned*)(ws + offs[4]);
        unsigned* colT   = (unsigned*)(ws + offs[5]);
        unsigned* startS = (unsigned*)(ws + offs[6]);
        unsigned* startD = (unsigned*)(ws + offs[7]);
        double*   gacc   = (double*)(ws + offs[8]);
        uint2*    ebufS  = (uint2*)(ws + offs[9]);
        uint4*    ebufD  = (uint4*)(ws + offs[10]);

        const int perS = (int)(((long long)E + SLC - 1) / SLC);
        const int NB_S = (NV + VPB - 1) / VPB;   // 512-var src bins
        const int NB_C = (NC + 255) >> 8;        // conT blocks (256/blk)
        const int NB_C2 = (NC + CPB - 1) / CPB;  // aggD blocks (1024-con bins)

        hipMemsetAsync(bufC,  0, (size_t)NC * BST * 4, stream);
        hipMemsetAsync(deg_c, 0, (size_t)NC * 4, stream);
        hipMemsetAsync(gacc,  0, 8, stream);

        // 1) S-sort by src-bin (tile-sorted coalesced scatter)
        k_hist<<<SLC, 1024, 0, stream>>>(src, hS, 0, E, perS, 9);
        k_coltot<<<NBINS / 256, 256, 0, stream>>>(hS, colT);
        k_prefix<<<1, 1024, 0, stream>>>(colT, startS);
        k_offs<<<NBINS / 256, 256, 0, stream>>>(hS, startS);
        k_scatS2<<<SLC, 1024, 0, stream>>>(src, dst, A, hS, ebufS, E, perS);

        // 2) degrees from sorted keys -> vcx
        k_cntS2<<<NB_S, 256, 0, stream>>>(ebufS, startS, var_c, var_x, vcx, NV);

        // 3) D chunks -> tile-sorted coalesced D scatter -> streaming v2c agg
        if (binc) {
            const int binsChunk = NBINS / nD;
            const int binsPer   = (binsChunk + SLC - 1) / SLC;
            for (int c = 0; c < nD; c++) {
                int B0 = c * binsChunk;
                k_histD2<<<SLC, 1024, 0, stream>>>(ebufS, startS, hD, B0, binsPer, binsChunk);
                k_coltot<<<NBINS / 256, 256, 0, stream>>>(hD, colT);
                k_prefix<<<1, 1024, 0, stream>>>(colT, startD);
                k_offs<<<NBINS / 256, 256, 0, stream>>>(hD, startD);
                k_scatD4<<<SLC, 1024, 0, stream>>>(ebufS, startS, hD, vcx, ebufD,
                                                   B0, binsPer, binsChunk, (unsigned)EcMax);
                k_aggD<<<NB_C2, 256, 0, stream>>>(ebufD, startD, Wv, bv, bufC, deg_c, NC);
            }
        } else {
            const int perD = (int)((EcMax + SLC - 1) / SLC);
            for (int c = 0; c < nD; c++) {
                long long cb = (long long)c * EcMax;
                long long ce = cb + EcMax; if (ce > E) ce = E;
                k_hist<<<SLC, 1024, 0, stream>>>(dst, hD, cb, ce, perD, DSH);
                k_coltot<<<NBINS / 256, 256, 0, stream>>>(hD, colT);
                k_prefix<<<1, 1024, 0, stream>>>(colT, startD);
                k_offs<<<NBINS / 256, 256, 0, stream>>>(hD, startD);
                k_scatD<<<SLC, 1024, 0, stream>>>(src, dst, A, hD, vcx, ebufD, cb, ce, perD);
                k_aggD<<<NB_C2, 256, 0, stream>>>(ebufD, startD, Wv, bv, bufC, deg_c, NC);
            }
        }
        k_conT<<<NB_C, 256, 0, stream>>>(bufC, deg_c, W2, b2, NC);

        // 4) fused c2v aggregate + MLP + mean
        k_aggS<<<NB_S, 256, 0, stream>>>(ebufS, startS, bufC, vcx, W2, b2,
                                         Wo1, bo1, Wo2, bo2, Wo3, bo3, gacc, NV);
        k_out<<<1, 1, 0, stream>>>(gacc, (float*)d_out, NV);
    } else {
        // round-1 fallback
        const int B = 256;
        float* fbufV = (float*)ws;
        float* fbufC = (float*)(ws + (size_t)NV * ST * 4);
        float* deg_v = (float*)(ws + (size_t)(NV + NC) * ST * 4);
        float* deg_c = deg_v + NV;
        size_t acc_off = ((size_t)(NV + NC) * ST * 4 + (size_t)(NV + NC) * 4 + 7) & ~(size_t)7;
        double* acc = (double*)(ws + acc_off);

        hipMemsetAsync(deg_v, 0, (size_t)(NV + NC) * 4, stream);
        hipMemsetAsync(fbufC, 0, (size_t)NC * ST * 4, stream);
        hipMemsetAsync(acc, 0, sizeof(double), stream);

        k_degree<<<(E + B - 1) / B, B, 0, stream>>>(src, dst, deg_v, deg_c, E);
        k_norm<<<(NV + NC + B - 1) / B, B, 0, stream>>>(deg_v, NV + NC);
        k_var_emb<<<(NV + B - 1) / B, B, 0, stream>>>(var_c, var_x, deg_v, Wv, bv, W2, fbufV, NV);

        long long tE = (long long)E * 5;
        k_edge<<<(int)((tE + B - 1) / B), B, 0, stream>>>(src, dst, A, fbufV, fbufC, E);
        k_con<<<(NC + B - 1) / B, B, 0, stream>>>(fbufC, deg_c, W2, b2, NC);

        hipMemsetAsync(fbufV, 0, (size_t)NV * ST * 4, stream);
        k_edge<<<(int)((tE + B - 1) / B), B, 0, stream>>>(dst, src, A, fbufC, fbufV, E);

        k_final<<<(NV + B - 1) / B, B, 0, stream>>>(fbufV, deg_v, b2, Wo1, bo1, Wo2, bo2, Wo3, bo3, acc, NV);
        k_out<<<1, 1, 0, stream>>>(acc, (float*)d_out, NV);
    }
}